// Round 2
// baseline (330.188 us; speedup 1.0000x reference)
//
#include <hip/hip_runtime.h>

// FSUConv2d stochastic-computing conv — TLP-maximized two-kernel version.
// N=8, C=32, H=W=16, OC=64, K=3, PAD=1, RLEN=256, CKK=288, B=2048.
//
// out[n,o,h,w] = sum_k [ x_k ? (w_bin[o,k] > rev8(i1)) : !(w_bin[o,k] > rev8(i0)) ]
//               + (b_bin[o] > rev8(brdx[o]))
//
// Identities:
//  * rng[idx % 256] == bitrev8(idx); for idx in [0,256), __brev(idx) == rev8<<24.
//  * (w > rev8)  <=>  wkey > __brev(idx)  where wkey = sat32(w<<24)
//    (w integral in [0,256]; 256 -> 0xFFFFFFFF always wins). wkey precomputed
//    once -> per element-side just v_bfrev + v_cmp.
//  * per-element result is ONE BIT -> wave-wide __ballot + __popcll (SALU),
//    no shuffle tree.
//
// Kernel 1 (fsu_pre): precompute into workspace
//   xm[2048][8]  u64 ballot masks of the unfolded x (e=0..3 main chunks
//                k=lane*4+e; e=4..7 tail chunks k=256+(lane&7)*4+(e-4),
//                bits 8..63 of tail masks are don't-care)
//   wkey[64][288] u32 saturated comparison keys
//   bb[64]       f32 bias bits
// Kernel 2 (fsu_stream): 8192 blocks x 4 waves, no LDS, no syncthreads.
// Wave handles 4 output rows with an explicit depth-2 register pipeline,
// sched_barrier(0)-fenced so loads stay clustered ahead of compute.

#define CH   32
#define HH   16
#define WW   16
#define OCN  64
#define CKK  288
#define LL   256     // H*W
#define BB   2048    // N*H*W

// workspace layout (bytes); total 205056 (< any sane ws_size)
#define WS_XM_OFF 0               // 2048*8*8  = 131072
#define WS_WK_OFF 131072          // 64*288*4  = 73728
#define WS_BB_OFF 204800          // 64*4      = 256

__device__ __forceinline__ float unf_val(const float* __restrict__ x,
                                         int n, int h, int w0, int k) {
    int c  = k / 9;
    int r  = k - c * 9;
    int kh = r / 3;
    int kw = r - kh * 3;
    int ih = h + kh - 1;
    int iw = w0 + kw - 1;
    float v = 0.f;
    if ((unsigned)ih < 16u && (unsigned)iw < 16u)
        v = x[((n * CH + c) * HH + ih) * WW + iw];
    return v;
}

__global__ __launch_bounds__(256) void fsu_pre(
    const float* __restrict__ x, const float* __restrict__ w_bin,
    const float* __restrict__ b_bin, const int* __restrict__ brdx,
    unsigned long long* __restrict__ xm, unsigned* __restrict__ wk,
    float* __restrict__ bb)
{
    if (blockIdx.x == 512) {
        // weight keys + bias bits
        for (int i = threadIdx.x; i < OCN * CKK; i += 256) {
            unsigned wi = (unsigned)w_bin[i];       // integral in [0,256]
            wk[i] = (wi >= 256u) ? 0xFFFFFFFFu : (wi << 24);
        }
        if (threadIdx.x < OCN) {
            int o = threadIdx.x;
            float rv = (float)(__brev((unsigned)brdx[o]) >> 24);
            bb[o] = (b_bin[o] > rv) ? 1.f : 0.f;
        }
        return;
    }
    // unfold one patch per wave into 8 ballot masks
    const int wave = threadIdx.x >> 6;
    const int lane = threadIdx.x & 63;
    const int b = blockIdx.x * 4 + wave;    // patch in [0, 2048)
    const int n = b >> 8, l = b & 255;
    const int h = l >> 4, w0 = l & 15;

    unsigned long long m[8];
    #pragma unroll
    for (int e = 0; e < 4; ++e)
        m[e] = __ballot(unf_val(x, n, h, w0, lane * 4 + e) != 0.f);
    #pragma unroll
    for (int e = 0; e < 4; ++e)   // tail, broadcast across lane groups of 8
        m[4 + e] = __ballot(unf_val(x, n, h, w0, 256 + (lane & 7) * 4 + e) != 0.f);

    if (lane == 0) {
        #pragma unroll
        for (int e = 0; e < 8; ++e) xm[(size_t)b * 8 + e] = m[e];
    }
}

struct Row {
    int4  a, c;    // wrdx1 / wrdx0, k = lane*4 .. +3
    uint4 k;       // wkey, same k
    int4  at, ct;  // tail k = 256+(lane&7)*4 .. +3 (broadcast)
    uint4 kt;
};

__device__ __forceinline__ void load_row(Row& r, const int* __restrict__ p1,
                                         const int* __restrict__ p0,
                                         const unsigned* __restrict__ pw,
                                         int j, int lane, int tl) {
    const int4*  q1 = (const int4*)(p1 + j * CKK);
    const int4*  q0 = (const int4*)(p0 + j * CKK);
    const uint4* qw = (const uint4*)(pw + j * CKK);
    r.a  = q1[lane]; r.c  = q0[lane]; r.k  = qw[lane];
    r.at = q1[tl];   r.ct = q0[tl];   r.kt = qw[tl];
}

// bit = x ? (wkey > brev(i1)) : !(wkey > brev(i0)), assembled as 64-bit mask
__device__ __forceinline__ unsigned long long chunkm(unsigned k, int a1, int a0,
                                                     unsigned long long xm) {
    unsigned long long m1 = __ballot(k > __brev((unsigned)a1));
    unsigned long long m0 = __ballot(k > __brev((unsigned)a0));
    return (xm & m1) | (~xm & ~m0);
}

__global__ __launch_bounds__(256) void fsu_stream(
    const int* __restrict__ wrdx1, const int* __restrict__ wrdx0,
    const unsigned* __restrict__ wk, const unsigned long long* __restrict__ xm,
    const float* __restrict__ bb, float* __restrict__ out)
{
    const int blk  = blockIdx.x;         // b*4 + og
    const int b    = blk >> 2;
    const int og   = blk & 3;
    const int wave = threadIdx.x >> 6;
    const int lane = threadIdx.x & 63;
    const int obase = og * 16 + wave * 4; // this wave: rows obase..obase+3
    const int n = b >> 8, l = b & 255;
    const int tl = 64 + (lane & 7);

    // patch x-masks: uniform address -> scalar loads, SGPR-resident
    const unsigned long long* xb = xm + (size_t)b * 8;
    const unsigned long long xm0 = xb[0], xm1 = xb[1], xm2 = xb[2], xm3 = xb[3];
    const unsigned long long xt0 = xb[4], xt1 = xb[5], xt2 = xb[6], xt3 = xb[7];

    const int* p1 = wrdx1 + ((size_t)b * OCN + obase) * CKK;
    const int* p0 = wrdx0 + ((size_t)b * OCN + obase) * CKK;
    const unsigned* pw = wk + (size_t)obase * CKK;
    float* po = out + ((size_t)n * OCN + obase) * LL + l;

    auto docompute = [&](const Row& r, int j) {
        unsigned cnt = 0;
        cnt += __popcll(chunkm(r.k.x,  r.a.x,  r.c.x,  xm0));
        cnt += __popcll(chunkm(r.k.y,  r.a.y,  r.c.y,  xm1));
        cnt += __popcll(chunkm(r.k.z,  r.a.z,  r.c.z,  xm2));
        cnt += __popcll(chunkm(r.k.w,  r.a.w,  r.c.w,  xm3));
        // tail: elements broadcast 8x across the wave -> count bits 0..7 only
        cnt += __popcll(chunkm(r.kt.x, r.at.x, r.ct.x, xt0) & 0xFFull);
        cnt += __popcll(chunkm(r.kt.y, r.at.y, r.ct.y, xt1) & 0xFFull);
        cnt += __popcll(chunkm(r.kt.z, r.at.z, r.ct.z, xt2) & 0xFFull);
        cnt += __popcll(chunkm(r.kt.w, r.at.w, r.ct.w, xt3) & 0xFFull);
        if (lane == 0)
            po[j * LL] = (float)cnt + bb[obase + j];
    };

    // depth-2 register pipeline; sched_barrier(0) pins load clusters ahead
    // of compute so the compiler cannot serialize load->wait->compute per row.
    Row A, B;
    load_row(A, p1, p0, pw, 0, lane, tl);
    load_row(B, p1, p0, pw, 1, lane, tl);
    __builtin_amdgcn_sched_barrier(0);
    docompute(A, 0);
    load_row(A, p1, p0, pw, 2, lane, tl);
    __builtin_amdgcn_sched_barrier(0);
    docompute(B, 1);
    load_row(B, p1, p0, pw, 3, lane, tl);
    __builtin_amdgcn_sched_barrier(0);
    docompute(A, 2);
    docompute(B, 3);
}

extern "C" void kernel_launch(void* const* d_in, const int* in_sizes, int n_in,
                              void* d_out, int out_size, void* d_ws, size_t ws_size,
                              hipStream_t stream) {
    const float* x     = (const float*)d_in[0];
    const float* w_bin = (const float*)d_in[1];
    const float* b_bin = (const float*)d_in[2];
    // d_in[3] = rng — replaced by closed-form bit-reversal
    const int*   wrdx1 = (const int*)d_in[4];
    const int*   wrdx0 = (const int*)d_in[5];
    const int*   brdx  = (const int*)d_in[6];
    float*       out   = (float*)d_out;

    unsigned long long* xm = (unsigned long long*)((char*)d_ws + WS_XM_OFF);
    unsigned*           wk = (unsigned*)((char*)d_ws + WS_WK_OFF);
    float*              bb = (float*)((char*)d_ws + WS_BB_OFF);

    // same stream -> fsu_stream starts after fsu_pre completes
    fsu_pre<<<dim3(513), dim3(256), 0, stream>>>(x, w_bin, b_bin, brdx, xm, wk, bb);
    fsu_stream<<<dim3(BB * 4), dim3(256), 0, stream>>>(wrdx1, wrdx0, wk, xm, bb, out);
}

// Round 3
// 324.471 us; speedup vs baseline: 1.0176x; 1.0176x over previous
//
#include <hip/hip_runtime.h>

// FSUConv2d stochastic-computing conv — global_load_lds streaming version.
// N=8, C=32, H=W=16, OC=64, K=3, PAD=1, RLEN=256, CKK=288, B=2048.
//
// out[n,o,h,w] = sum_k [ x_k ? (w_bin[o,k] > rev8(i1)) : !(w_bin[o,k] > rev8(i0)) ]
//               + (b_bin[o] > rev8(brdx[o]))
//
// Identities:
//  * rng[idx % 256] == bitrev8(idx); (w > rev8) <=> wkey > __brev(idx) where
//    wkey = sat32(w<<24) (w integral in [0,256]; 256 -> 0xFFFFFFFF).
//  * per-element result is ONE BIT -> wave-wide __ballot + __popcll, no shfl.
//
// Structure (the round-0..2 lesson: compiler register-minimizes and
// serializes vector loads -> latency-bound at ~110us regardless of source
// pipelining): move the 302 MB wrdx stream through LDS via
// __builtin_amdgcn_global_load_lds with COUNTED s_waitcnt vmcnt(4) (never 0
// in the loop), so MLP does not depend on VGPR allocation.
//   grid 2048 = 128 b-chunks x 16 o-groups; 4 waves/block; wave = one fixed
//   o, streams 16 patches. Weight keys live in 8 VGPRs (loaded once).
//   x ballot-masks precomputed by fsu_pre into ws, DMA'd to LDS at prologue,
//   consumed via broadcast ds_read + readfirstlane (SGPR masks, zero vmcnt).
//   Loop vmem = exactly 4 DMA/row-pair + 1 store -> vmcnt(4) is exact.

#define CH   32
#define HH   16
#define WW   16
#define OCN  64
#define CKK  288
#define LL   256     // H*W
#define BB   2048    // N*H*W
#define BPW  16      // patches per wave / per block
#define ROWSTRIDE (OCN * CKK)   // ints between same-o rows of consecutive b

__device__ __forceinline__ unsigned wkey(float wv) {
    unsigned wi = (unsigned)wv;                 // integral in [0,256]
    return (wi >= 256u) ? 0xFFFFFFFFu : (wi << 24);
}

__device__ __forceinline__ void async16(const void* g, void* l) {
    __builtin_amdgcn_global_load_lds(
        (const __attribute__((address_space(1))) void*)g,
        (__attribute__((address_space(3))) void*)l, 16, 0, 0);
}

__device__ __forceinline__ unsigned long long rfl64(unsigned long long v) {
    unsigned lo = __builtin_amdgcn_readfirstlane((unsigned)v);
    unsigned hi = __builtin_amdgcn_readfirstlane((unsigned)(v >> 32));
    return ((unsigned long long)hi << 32) | lo;
}

// ---------------- kernel 1: unfold x into ballot masks ----------------
__device__ __forceinline__ float unf_val(const float* __restrict__ x,
                                         int n, int h, int w0, int k) {
    int c  = k / 9;
    int r  = k - c * 9;
    int kh = r / 3;
    int kw = r - kh * 3;
    int ih = h + kh - 1;
    int iw = w0 + kw - 1;
    float v = 0.f;
    if ((unsigned)ih < 16u && (unsigned)iw < 16u)
        v = x[((n * CH + c) * HH + ih) * WW + iw];
    return v;
}

__global__ __launch_bounds__(256) void fsu_pre(
    const float* __restrict__ x, unsigned long long* __restrict__ xm)
{
    const int wave = threadIdx.x >> 6;
    const int lane = threadIdx.x & 63;
    const int b = blockIdx.x * 4 + wave;    // patch in [0, 2048)
    const int n = b >> 8, l = b & 255;
    const int h = l >> 4, w0 = l & 15;

    unsigned long long m[8];
    #pragma unroll
    for (int e = 0; e < 4; ++e)
        m[e] = __ballot(unf_val(x, n, h, w0, lane * 4 + e) != 0.f);
    #pragma unroll
    for (int e = 0; e < 4; ++e)   // tail, broadcast across lane groups of 8
        m[4 + e] = __ballot(unf_val(x, n, h, w0, 256 + (lane & 7) * 4 + e) != 0.f);

    if (lane == 0) {
        #pragma unroll
        for (int e = 0; e < 8; ++e) xm[(size_t)b * 8 + e] = m[e];
    }
}

// ---------------- kernel 2: stream wrdx via LDS DMA ----------------
// bit = x ? (wkey > brev(i1)) : !(wkey > brev(i0)), as a 64-bit wave mask
__device__ __forceinline__ unsigned long long chunkm(unsigned k, int a1, int a0,
                                                     unsigned long long xm) {
    unsigned long long m1 = __ballot(k > __brev((unsigned)a1));
    unsigned long long m0 = __ballot(k > __brev((unsigned)a0));
    return (xm & m1) | (~xm & ~m0);
}

__global__ __launch_bounds__(256) void fsu_stream(
    const int* __restrict__ wrdx1, const int* __restrict__ wrdx0,
    const float* __restrict__ w_bin, const float* __restrict__ b_bin,
    const int* __restrict__ brdx,
    const unsigned long long* __restrict__ xm,
    float* __restrict__ out)
{
    // per-wave double buffer: [wrdx1 row 1152B | wrdx0 row 1152B] x 2
    __shared__ __align__(16) int buf[4][2][2 * CKK];       // 18432 B
    __shared__ __align__(16) unsigned long long xml[BPW * 8]; // 1024 B

    const int wave = threadIdx.x >> 6;
    const int lane = threadIdx.x & 63;
    const int og   = blockIdx.x & 15;      // o-group of 4
    const int bch  = blockIdx.x >> 4;      // b-chunk of 16
    const int o    = og * 4 + wave;        // this wave's fixed output row
    const int b0   = bch * BPW;

    // ---- prologue (all pre-loop vmem drains at the __syncthreads) ----
    // weight keys for row o, lane-distributed: 8 VGPRs total
    const float* pw = w_bin + (size_t)o * CKK;
    float4 wm = ((const float4*)pw)[lane];
    float4 wt = ((const float4*)pw)[64 + (lane & 7)];
    uint4 km = make_uint4(wkey(wm.x), wkey(wm.y), wkey(wm.z), wkey(wm.w));
    uint4 kt = make_uint4(wkey(wt.x), wkey(wt.y), wkey(wt.z), wkey(wt.w));
    float bbv = (b_bin[o] > (float)(__brev((unsigned)brdx[o]) >> 24)) ? 1.f : 0.f;

    // x-masks for the block's 16 patches -> LDS (one 1024B DMA by wave 0)
    if (wave == 0)
        async16((const char*)(xm + (size_t)b0 * 8) + lane * 16,
                (char*)xml);
    __syncthreads();   // drains vmcnt for all waves -> clean slate

    int* bufA = &buf[wave][0][0];
    int* bufB = &buf[wave][1][0];

    const int* g1 = wrdx1 + ((size_t)b0 * OCN + o) * CKK + lane * 4;
    const int* g0 = wrdx0 + ((size_t)b0 * OCN + o) * CKK + lane * 4;
    const int* t1 = wrdx1 + ((size_t)b0 * OCN + o) * CKK + 256 + (lane & 7) * 4;
    const int* t0 = wrdx0 + ((size_t)b0 * OCN + o) * CKK + 256 + (lane & 7) * 4;

    // 4 DMA per row-pair: [0,1024) [1152,2176) full-wave; tails lanes 0-7
    auto issue = [&](int j, int* dst) {
        __builtin_amdgcn_sched_barrier(0);
        async16(g1 + (size_t)j * ROWSTRIDE, dst);
        async16(g0 + (size_t)j * ROWSTRIDE, dst + CKK);
        if (lane < 8) {
            async16(t1 + (size_t)j * ROWSTRIDE, (char*)dst + 1024);
            async16(t0 + (size_t)j * ROWSTRIDE, (char*)dst + 4 * CKK + 1024);
        }
    };

    auto compute = [&](const int* src, int j) {
        // masks: broadcast ds_read (free) -> SGPR via readfirstlane
        const unsigned long long* xr = xml + j * 8;
        unsigned long long x0 = rfl64(xr[0]), x1 = rfl64(xr[1]);
        unsigned long long x2 = rfl64(xr[2]), x3 = rfl64(xr[3]);
        unsigned long long y0 = rfl64(xr[4]), y1 = rfl64(xr[5]);
        unsigned long long y2 = rfl64(xr[6]), y3 = rfl64(xr[7]);

        int4 a  = *(const int4*)((const char*)src + lane * 16);
        int4 at = *(const int4*)((const char*)src + 1024 + (lane & 7) * 16);
        int4 c  = *(const int4*)((const char*)src + 4 * CKK + lane * 16);
        int4 ct = *(const int4*)((const char*)src + 4 * CKK + 1024 + (lane & 7) * 16);

        unsigned cnt = 0;
        cnt += __popcll(chunkm(km.x, a.x, c.x, x0));
        cnt += __popcll(chunkm(km.y, a.y, c.y, x1));
        cnt += __popcll(chunkm(km.z, a.z, c.z, x2));
        cnt += __popcll(chunkm(km.w, a.w, c.w, x3));
        cnt += __popcll(chunkm(kt.x, at.x, ct.x, y0) & 0xFFull);
        cnt += __popcll(chunkm(kt.y, at.y, ct.y, y1) & 0xFFull);
        cnt += __popcll(chunkm(kt.z, at.z, ct.z, y2) & 0xFFull);
        cnt += __popcll(chunkm(kt.w, at.w, ct.w, y3) & 0xFFull);

        if (lane == 0) {
            int bcur = b0 + j;
            int n = bcur >> 8, l = bcur & 255;
            out[((size_t)n * OCN + o) * LL + l] = (float)cnt + bbv;
        }
    };

    // ---- counted-vmcnt pipeline: 4 DMAs (next row) always in flight ----
    issue(0, bufA);
    #pragma unroll
    for (int p = 0; p < 8; ++p) {
        const int j = p * 2;
        issue(j + 1, bufB);
        asm volatile("s_waitcnt vmcnt(4)" ::: "memory");  // row j landed
        __builtin_amdgcn_sched_barrier(0);
        compute(bufA, j);
        if (p < 7) {
            issue(j + 2, bufA);
            asm volatile("s_waitcnt vmcnt(4)" ::: "memory");  // row j+1 landed
        } else {
            asm volatile("s_waitcnt vmcnt(0)" ::: "memory");  // final drain
        }
        __builtin_amdgcn_sched_barrier(0);
        compute(bufB, j + 1);
    }
}

extern "C" void kernel_launch(void* const* d_in, const int* in_sizes, int n_in,
                              void* d_out, int out_size, void* d_ws, size_t ws_size,
                              hipStream_t stream) {
    const float* x     = (const float*)d_in[0];
    const float* w_bin = (const float*)d_in[1];
    const float* b_bin = (const float*)d_in[2];
    // d_in[3] = rng — replaced by closed-form bit-reversal
    const int*   wrdx1 = (const int*)d_in[4];
    const int*   wrdx0 = (const int*)d_in[5];
    const int*   brdx  = (const int*)d_in[6];
    float*       out   = (float*)d_out;

    unsigned long long* xm = (unsigned long long*)d_ws;  // 2048*8*8 = 131072 B

    fsu_pre<<<dim3(BB / 4), dim3(256), 0, stream>>>(x, xm);
    fsu_stream<<<dim3(BB), dim3(256), 0, stream>>>(wrdx1, wrdx0, w_bin, b_bin,
                                                   brdx, xm, out);
}